// Round 4
// baseline (173.602 us; speedup 1.0000x reference)
//
#include <hip/hip_runtime.h>
#include <math.h>

#define N_ 2
#define L_ 2048
#define S_ 2048
#define H_ 8
#define D_ 64

#define BLK_L 256        // l-rows per block (4 waves x 64)
#define BS 64            // s-rows per K tile
#define SSPLIT 8
#define TILES (S_ / SSPLIT / BS)   // 4
#define KROW 80          // LDS row stride in shorts (160B) -> uniform-8 bank spread
#define KP 32            // ksum partial slices (S/64)

typedef __attribute__((ext_vector_type(8))) short short8;
typedef __attribute__((ext_vector_type(4))) short short4v;
typedef __attribute__((ext_vector_type(4))) float floatx4;

__device__ __forceinline__ float feat(float x) {
    // elu(x)+1 = x>0 ? x+1 : exp(x)
    return x > 0.0f ? x + 1.0f : __expf(x);
}
__device__ __forceinline__ short f2bf(float x) {
    unsigned u = __float_as_uint(x);
    unsigned r = (u + 0x7fffu + ((u >> 16) & 1u)) >> 16;   // round-nearest-even
    return (short)r;
}
__device__ __forceinline__ float bf2f(short h) {
    return __uint_as_float(((unsigned)(unsigned short)h) << 16);
}

// ---- K prep: featurize+mask K -> bf16 hi/lo in [N,H,S,D]; Ksum partials ----
__global__ __launch_bounds__(256) void kprep_kernel(const float* __restrict__ K,
        const float* __restrict__ kvmask, short* __restrict__ KH,
        short* __restrict__ KL, float* __restrict__ Kpart) {
    int nh = blockIdx.x;          // 16
    int sc = blockIdx.y;          // 32 chunks of 64 s-rows
    int n = nh >> 3, h = nh & 7;
    int t = threadIdx.x;
    int sr = t >> 4;              // 0..15
    int d4 = (t & 15) * 4;
    float sums[4] = {0.f, 0.f, 0.f, 0.f};
    #pragma unroll
    for (int p = 0; p < 4; ++p) {
        int s = sc * 64 + p * 16 + sr;
        float km = kvmask[n * S_ + s];
        float4 v = *(const float4*)(K + (((size_t)n * S_ + s) * H_ + h) * D_ + d4);
        float f0 = feat(v.x) * km, f1 = feat(v.y) * km;
        float f2 = feat(v.z) * km, f3 = feat(v.w) * km;
        sums[0] += f0; sums[1] += f1; sums[2] += f2; sums[3] += f3;
        short4v hi, lo;
        hi.x = f2bf(f0); lo.x = f2bf(f0 - bf2f(hi.x));
        hi.y = f2bf(f1); lo.y = f2bf(f1 - bf2f(hi.y));
        hi.z = f2bf(f2); lo.z = f2bf(f2 - bf2f(hi.z));
        hi.w = f2bf(f3); lo.w = f2bf(f3 - bf2f(hi.w));
        size_t o = ((size_t)nh * S_ + s) * 64 + d4;     // [N,H,S,D] contiguous rows
        *(short4v*)(KH + o) = hi;
        *(short4v*)(KL + o) = lo;
    }
    __shared__ float smf[16][64];
    #pragma unroll
    for (int j = 0; j < 4; ++j) smf[sr][d4 + j] = sums[j];
    __syncthreads();
    if (t < 64) {
        float s = 0.f;
        #pragma unroll
        for (int r = 0; r < 16; ++r) s += smf[r][t];
        Kpart[(sc * 16 + nh) * 64 + t] = s;
    }
}

// ---- row-max via compensated-bf16 MFMA; prefeaturized K, lean hot loop ----
__global__ __launch_bounds__(256, 4) void rowmax_mfma(
        const float* __restrict__ Q, const short* __restrict__ KH,
        const short* __restrict__ KL, const float* __restrict__ qmask,
        float* __restrict__ rowpart) {
    __shared__ short Kh[2][BS * KROW];
    __shared__ short Kl[2][BS * KROW];

    int nh = blockIdx.y;
    int n = nh >> 3, h = nh & 7;
    int t = threadIdx.x;
    int w = t >> 6, lane = t & 63;
    int quad = lane >> 4, l16 = lane & 15;
    int lblock = blockIdx.x * BLK_L;
    int z = blockIdx.z;

    // ---- prologue: featurize Q -> A fragments in registers (hi/lo bf16) ----
    // A-frag layout (16x16x32): m = lane&15, k = quad*8 + j
    short8 Ah[4][2], Al[4][2];
    #pragma unroll
    for (int lsub = 0; lsub < 4; ++lsub) {
        int lrow = lblock + w * 64 + lsub * 16 + l16;
        float qm = qmask[n * L_ + lrow];
        const float* qp = Q + (((size_t)n * L_ + lrow) * H_ + h) * D_ + quad * 8;
        #pragma unroll
        for (int ks = 0; ks < 2; ++ks) {
            float4 v0 = *(const float4*)(qp + ks * 32);
            float4 v1 = *(const float4*)(qp + ks * 32 + 4);
            float fv[8];
            fv[0] = feat(v0.x) * qm; fv[1] = feat(v0.y) * qm;
            fv[2] = feat(v0.z) * qm; fv[3] = feat(v0.w) * qm;
            fv[4] = feat(v1.x) * qm; fv[5] = feat(v1.y) * qm;
            fv[6] = feat(v1.z) * qm; fv[7] = feat(v1.w) * qm;
            short8 hi, lo;
            #pragma unroll
            for (int j = 0; j < 8; ++j) {
                short hb = f2bf(fv[j]);
                hi[j] = hb;
                lo[j] = f2bf(fv[j] - bf2f(hb));
            }
            Ah[lsub][ks] = hi;
            Al[lsub][ks] = lo;
        }
    }

    // staging: thread covers ids {t, t+256}; id -> (s = id>>3, granule g = id&7)
    // global: 1KB contiguous per wave-inst; LDS granule = 10s+g -> uniform-8 banks
    short8 svh[2], svl[2];
    auto loadreg = [&](int tile) {
        int sbase = z * (S_ / SSPLIT) + tile * BS;
        #pragma unroll
        for (int p = 0; p < 2; ++p) {
            int id = t + 256 * p;
            int s = id >> 3, g = id & 7;
            size_t o = ((size_t)nh * S_ + sbase + s) * 64 + g * 8;
            svh[p] = *(const short8*)(KH + o);
            svl[p] = *(const short8*)(KL + o);
        }
    };
    auto storelds = [&](int buf) {
        #pragma unroll
        for (int p = 0; p < 2; ++p) {
            int id = t + 256 * p;
            int s = id >> 3, g = id & 7;
            *(short8*)(&Kh[buf][s * KROW + g * 8]) = svh[p];
            *(short8*)(&Kl[buf][s * KROW + g * 8]) = svl[p];
        }
    };

    float rmax[4][4];
    #pragma unroll
    for (int i = 0; i < 4; ++i)
        #pragma unroll
        for (int r = 0; r < 4; ++r) rmax[i][r] = 0.f;   // dots >= 0

    loadreg(0);
    storelds(0);
    __syncthreads();

    for (int tile = 0; tile < TILES; ++tile) {
        int cur = tile & 1;
        if (tile + 1 < TILES) loadreg(tile + 1);   // loads fly during MFMA

        #pragma unroll
        for (int ssub = 0; ssub < 4; ++ssub) {
            // B-frag: n = lane&15 (s-row), k = quad*8 + j
            const short* bph = &Kh[cur][(ssub * 16 + l16) * KROW + quad * 8];
            const short* bpl = &Kl[cur][(ssub * 16 + l16) * KROW + quad * 8];
            short8 Bh0 = *(const short8*)(bph);
            short8 Bh1 = *(const short8*)(bph + 32);
            short8 Bl0 = *(const short8*)(bpl);
            short8 Bl1 = *(const short8*)(bpl + 32);
            #pragma unroll
            for (int lsub = 0; lsub < 4; ++lsub) {
                floatx4 acc = {0.f, 0.f, 0.f, 0.f};
                acc = __builtin_amdgcn_mfma_f32_16x16x32_bf16(Ah[lsub][0], Bh0, acc, 0, 0, 0);
                acc = __builtin_amdgcn_mfma_f32_16x16x32_bf16(Ah[lsub][1], Bh1, acc, 0, 0, 0);
                acc = __builtin_amdgcn_mfma_f32_16x16x32_bf16(Ah[lsub][0], Bl0, acc, 0, 0, 0);
                acc = __builtin_amdgcn_mfma_f32_16x16x32_bf16(Ah[lsub][1], Bl1, acc, 0, 0, 0);
                acc = __builtin_amdgcn_mfma_f32_16x16x32_bf16(Al[lsub][0], Bh0, acc, 0, 0, 0);
                acc = __builtin_amdgcn_mfma_f32_16x16x32_bf16(Al[lsub][1], Bh1, acc, 0, 0, 0);
                #pragma unroll
                for (int r = 0; r < 4; ++r)
                    rmax[lsub][r] = fmaxf(rmax[lsub][r], acc[r]);
            }
        }

        if (tile + 1 < TILES) storelds(1 - cur);   // fill other buffer
        __syncthreads();
    }

    // ---- epilogue: reduce across 16 column-lanes, write z-partial ----
    // C/D layout: col(s) = lane&15, row(l) = quad*4 + r
    #pragma unroll
    for (int lsub = 0; lsub < 4; ++lsub)
        #pragma unroll
        for (int r = 0; r < 4; ++r) {
            float m = rmax[lsub][r];
            m = fmaxf(m, __shfl_xor(m, 1, 64));
            m = fmaxf(m, __shfl_xor(m, 2, 64));
            m = fmaxf(m, __shfl_xor(m, 4, 64));
            m = fmaxf(m, __shfl_xor(m, 8, 64));
            if (l16 == 0) {
                int l = lblock + w * 64 + lsub * 16 + quad * 4 + r;
                rowpart[((size_t)z * 16 + nh) * L_ + l] = m;
            }
        }
}

// ---- finalize: Ksum reduce + mean + max + gate + masked write ----
__global__ __launch_bounds__(256) void finalize_kernel(
        const float* __restrict__ Q, const float* __restrict__ qmask,
        const float* __restrict__ Kpart, const float* __restrict__ rowpart,
        const float* __restrict__ W, const float* __restrict__ b,
        float* __restrict__ out) {
    int nh = blockIdx.y;
    int n = nh >> 3, h = nh & 7;
    int lblock = blockIdx.x * 64;
    int t = threadIdx.x;
    int w = t >> 6, lane = t & 63;

    float ks = 0.f;
    #pragma unroll 8
    for (int p = 0; p < KP; ++p)
        ks += Kpart[(p * 16 + nh) * 64 + lane];

    float w0 = W[0], w1 = W[1], bb = b[0];

    #pragma unroll 4
    for (int r = 0; r < 16; ++r) {
        int l = lblock + w * 16 + r;
        float q = Q[(((size_t)n * L_ + l) * H_ + h) * D_ + lane];
        float qm = qmask[n * L_ + l];
        float p = feat(q) * qm * ks;
        #pragma unroll
        for (int off = 32; off > 0; off >>= 1)
            p += __shfl_xor(p, off, 64);
        float mx = 0.f;
        #pragma unroll
        for (int zz = 0; zz < SSPLIT; ++zz)
            mx = fmaxf(mx, rowpart[((size_t)zz * 16 + nh) * L_ + l]);
        float g = 1.0f / (1.0f + __expf(-(w0 * p * (1.0f / S_) + w1 * mx + bb)));
        out[(((size_t)n * L_ + l) * H_ + h) * D_ + lane] = q * qm * g;
    }
}

extern "C" void kernel_launch(void* const* d_in, const int* in_sizes, int n_in,
                              void* d_out, int out_size, void* d_ws, size_t ws_size,
                              hipStream_t stream) {
    const float* Q      = (const float*)d_in[0];
    const float* K      = (const float*)d_in[1];
    // d_in[2] = values: masked in reference but unused downstream
    const float* qmask  = (const float*)d_in[3];
    const float* kvmask = (const float*)d_in[4];
    const float* W      = (const float*)d_in[5];
    const float* b      = (const float*)d_in[6];
    float* out = (float*)d_out;

    char* ws = (char*)d_ws;
    float* Kpart   = (float*)(ws);                      // 32*16*64 f = 128 KB
    float* rowpart = (float*)(ws + 131072);             // 8*16*2048 f = 1 MB
    short* KH      = (short*)(ws + 131072 + 1048576);   // 4 MB
    short* KL      = (short*)(ws + 131072 + 1048576 + 4194304);  // 4 MB

    kprep_kernel<<<dim3(N_ * H_, S_ / 64), 256, 0, stream>>>(K, kvmask, KH, KL, Kpart);
    rowmax_mfma<<<dim3(L_ / BLK_L, N_ * H_, SSPLIT), 256, 0, stream>>>(
        Q, KH, KL, qmask, rowpart);
    finalize_kernel<<<dim3(L_ / 64, N_ * H_), 256, 0, stream>>>(
        Q, qmask, Kpart, rowpart, W, b, out);
}